// Round 2
// baseline (882.519 us; speedup 1.0000x reference)
//
#include <hip/hip_runtime.h>

// Sizes fixed by the problem but derived from in_sizes at launch.
#define HID 64
#define INDIM 128

__device__ __forceinline__ float softplusf(float x) {
    // log(1+exp(x)) stable
    return fmaxf(x, 0.f) + log1pf(expf(-fabsf(x)));
}

// ---------------- init: deg = 1 (self loop), zero small accumulators -------
__global__ __launch_bounds__(256) void k_init(float* deg, float* smallbuf, int N) {
    int i = blockIdx.x * 256 + threadIdx.x;
    if (i < N) deg[i] = 1.0f;
    if (i < 130) smallbuf[i] = 0.0f;  // sumvec[64] | svec[64] | loss[2]
}

// ---------------- degree count over dst ------------------------------------
__global__ __launch_bounds__(256) void k_degcount(const int* __restrict__ dst,
                                                  float* __restrict__ deg, int E) {
    int e = blockIdx.x * 256 + threadIdx.x;
    if (e < E) atomicAdd(&deg[dst[e]], 1.0f);
}

// ---------------- deg -> rsqrt(deg) in place --------------------------------
__global__ __launch_bounds__(256) void k_dinv(float* deg, int N) {
    int i = blockIdx.x * 256 + threadIdx.x;
    if (i < N) deg[i] = rsqrtf(deg[i]);
}

// ---------------- H = x @ W  (N x 128) @ (128 x 64) ------------------------
__global__ __launch_bounds__(256) void k_gemm(const float* __restrict__ x,
                                              const float* __restrict__ W,
                                              float* __restrict__ H, int N) {
    __shared__ float Xs[64 * 132];   // 64 rows, stride 132 (pad: kills 4-way conflict)
    __shared__ float Ws[128 * 64];
    int tid = threadIdx.x;
    int row0 = blockIdx.x * 64;

    const float4* W4 = (const float4*)W;
    float4* Ws4 = (float4*)Ws;
#pragma unroll
    for (int i = 0; i < 8; i++) Ws4[tid + 256 * i] = W4[tid + 256 * i];

#pragma unroll
    for (int i = 0; i < 8; i++) {
        int j = tid + 256 * i;          // 0..2047 float4s
        int r = j >> 5, c4 = j & 31;
        int row = row0 + r;
        float4 v = make_float4(0.f, 0.f, 0.f, 0.f);
        if (row < N) v = *(const float4*)(x + row * INDIM + c4 * 4);
        *(float4*)(&Xs[r * 132 + c4 * 4]) = v;
    }
    __syncthreads();

    int tx = tid & 15;        // col group: cols tx*4 .. tx*4+3
    int ty = tid >> 4;        // row group: rows ty*4 .. ty*4+3
    float acc[4][4] = {};
    const float* xa = &Xs[(ty * 4) * 132];
#pragma unroll 4
    for (int k = 0; k < 128; k++) {
        float4 b = *(const float4*)(&Ws[k * 64 + tx * 4]);
#pragma unroll
        for (int i = 0; i < 4; i++) {
            float a = xa[i * 132 + k];
            acc[i][0] = fmaf(a, b.x, acc[i][0]);
            acc[i][1] = fmaf(a, b.y, acc[i][1]);
            acc[i][2] = fmaf(a, b.z, acc[i][2]);
            acc[i][3] = fmaf(a, b.w, acc[i][3]);
        }
    }
#pragma unroll
    for (int i = 0; i < 4; i++) {
        int row = row0 + ty * 4 + i;
        if (row < N)
            *(float4*)(&H[row * HID + tx * 4]) =
                make_float4(acc[i][0], acc[i][1], acc[i][2], acc[i][3]);
    }
}

// ---------------- self-loop init: posAcc = H*dinv^2, negAcc = H[perm]*dinv^2
__global__ __launch_bounds__(256) void k_selfloop(const float* __restrict__ H,
                                                  const int* __restrict__ perm,
                                                  const float* __restrict__ dinv,
                                                  float* __restrict__ posAcc,
                                                  float* __restrict__ negAcc, int N) {
    int idx = blockIdx.x * 256 + threadIdx.x;   // over N*64
    if (idx >= N * HID) return;
    int n = idx >> 6, d = idx & 63;
    float w = dinv[n];
    w *= w;
    posAcc[idx] = H[idx] * w;
    negAcc[idx] = H[perm[n] * HID + d] * w;
}

// ---------------- edge scatter: wave per edge, lane = dim ------------------
__global__ __launch_bounds__(256) void k_edge(const int* __restrict__ src,
                                              const int* __restrict__ dst,
                                              const int* __restrict__ perm,
                                              const float* __restrict__ dinv,
                                              const float* __restrict__ H,
                                              float* __restrict__ posAcc,
                                              float* __restrict__ negAcc, int E) {
    int w = (blockIdx.x * 256 + threadIdx.x) >> 6;
    int lane = threadIdx.x & 63;
    if (w >= E) return;
    int s = src[w];
    int t = dst[w];
    int p = perm[s];
    float nrm = dinv[s] * dinv[t];
    float hv = H[s * HID + lane] * nrm;
    float hq = H[p * HID + lane] * nrm;
    atomicAdd(&posAcc[t * HID + lane], hv);
    atomicAdd(&negAcc[t * HID + lane], hq);
}

// ---------------- PReLU (in place) + column sum of pos ---------------------
__global__ __launch_bounds__(256) void k_act_sum(float* __restrict__ pos,
                                                 float* __restrict__ neg,
                                                 const float* __restrict__ b,
                                                 const float* __restrict__ a,
                                                 float* __restrict__ sumvec, int N) {
    int lane = threadIdx.x & 63;
    int wid = (blockIdx.x * 256 + threadIdx.x) >> 6;
    int nw = gridDim.x * 4;
    float bd = b[lane], ad = a[lane];
    float accP = 0.f;
    for (int n = wid; n < N; n += nw) {
        float v = pos[n * HID + lane] + bd;
        v = v > 0.f ? v : v * ad;
        pos[n * HID + lane] = v;
        accP += v;
        float u = neg[n * HID + lane] + bd;
        u = u > 0.f ? u : u * ad;
        neg[n * HID + lane] = u;
    }
    __shared__ float red[4][64];
    int w = threadIdx.x >> 6;
    red[w][lane] = accP;
    __syncthreads();
    if (w == 0) {
        float s = red[0][lane] + red[1][lane] + red[2][lane] + red[3][lane];
        atomicAdd(&sumvec[lane], s);
    }
}

// ---------------- discriminator: summary = sigmoid(mean), s = Wd @ summary -
__global__ void k_disc(const float* __restrict__ sumvec, const float* __restrict__ Wd,
                       float* __restrict__ svec, int N) {
    __shared__ float summ[64];
    int t = threadIdx.x;  // 64 threads
    summ[t] = 1.f / (1.f + expf(-sumvec[t] / (float)N));
    __syncthreads();
    float s = 0.f;
#pragma unroll
    for (int j = 0; j < 64; j++) s += Wd[t * 64 + j] * summ[j];
    svec[t] = s;
}

// ---------------- logits + softplus sums -----------------------------------
__global__ __launch_bounds__(256) void k_loss(const float* __restrict__ pos,
                                              const float* __restrict__ neg,
                                              const float* __restrict__ svec,
                                              float* __restrict__ lossAcc, int N) {
    int lane = threadIdx.x & 63;
    int wid = (blockIdx.x * 256 + threadIdx.x) >> 6;
    int nw = gridDim.x * 4;
    float sd = svec[lane];
    float l1 = 0.f, l2 = 0.f;
    for (int n = wid; n < N; n += nw) {
        float p = pos[n * HID + lane] * sd;
        float q = neg[n * HID + lane] * sd;
#pragma unroll
        for (int off = 32; off; off >>= 1) {
            p += __shfl_xor(p, off);
            q += __shfl_xor(q, off);
        }
        if (lane == 0) {
            l1 += softplusf(-p);
            l2 += softplusf(q);
        }
    }
    __shared__ float redA[4], redB[4];
    int w = threadIdx.x >> 6;
    if (lane == 0) { redA[w] = l1; redB[w] = l2; }
    __syncthreads();
    if (threadIdx.x == 0) {
        atomicAdd(&lossAcc[0], redA[0] + redA[1] + redA[2] + redA[3]);
        atomicAdd(&lossAcc[1], redB[0] + redB[1] + redB[2] + redB[3]);
    }
}

// ---------------- final scalar ---------------------------------------------
__global__ void k_final(const float* __restrict__ lossAcc, float* __restrict__ out, int N) {
    out[0] = (lossAcc[0] + lossAcc[1]) / (float)N;
}

extern "C" void kernel_launch(void* const* d_in, const int* in_sizes, int n_in,
                              void* d_out, int out_size, void* d_ws, size_t ws_size,
                              hipStream_t stream) {
    const float* x      = (const float*)d_in[0];
    const float* W_gcn  = (const float*)d_in[1];
    const float* b_gcn  = (const float*)d_in[2];
    const float* prelu_a= (const float*)d_in[3];
    const float* W_disc = (const float*)d_in[4];
    const int*   eidx   = (const int*)d_in[5];
    const int*   perm   = (const int*)d_in[6];

    int N = in_sizes[0] / INDIM;      // 100000
    int E = in_sizes[5] / 2;          // 1600000
    const int* src = eidx;
    const int* dst = eidx + E;

    // workspace layout (floats)
    float* ws = (float*)d_ws;
    size_t NH = (size_t)N * HID;      // 6.4M
    float* H      = ws;               // NH
    float* posAcc = ws + NH;          // NH
    float* negAcc = ws + 2 * NH;      // NH
    float* deg    = ws + 3 * NH;      // N  (becomes dinv in place)
    float* smallb = ws + 3 * NH + N;  // 130: sumvec[64] svec[64] loss[2]
    float* sumvec = smallb;
    float* svec   = smallb + 64;
    float* lossAcc= smallb + 128;

    int nblk;

    nblk = (N + 256 + 255) / 256;
    k_init<<<nblk, 256, 0, stream>>>(deg, smallb, N);

    nblk = (E + 255) / 256;
    k_degcount<<<nblk, 256, 0, stream>>>(dst, deg, E);

    nblk = (N + 255) / 256;
    k_dinv<<<nblk, 256, 0, stream>>>(deg, N);

    nblk = (N + 63) / 64;
    k_gemm<<<nblk, 256, 0, stream>>>(x, W_gcn, H, N);

    nblk = (N * HID + 255) / 256;
    k_selfloop<<<nblk, 256, 0, stream>>>(H, perm, deg, posAcc, negAcc, N);

    nblk = (int)(((long long)E * 64 + 255) / 256);
    k_edge<<<nblk, 256, 0, stream>>>(src, dst, perm, deg, H, posAcc, negAcc, E);

    k_act_sum<<<512, 256, 0, stream>>>(posAcc, negAcc, b_gcn, prelu_a, sumvec, N);

    k_disc<<<1, 64, 0, stream>>>(sumvec, W_disc, svec, N);

    k_loss<<<512, 256, 0, stream>>>(posAcc, negAcc, svec, lossAcc, N);

    k_final<<<1, 1, 0, stream>>>(lossAcc, (float*)d_out, N);
}

// Round 3
// 457.708 us; speedup vs baseline: 1.9281x; 1.9281x over previous
//
#include <hip/hip_runtime.h>

#define HID 64
#define INDIM 128

__device__ __forceinline__ float softplusf(float x) {
    return fmaxf(x, 0.f) + log1pf(expf(-fabsf(x)));
}

// ---------------- init: zero cnt + small accumulators ----------------------
__global__ __launch_bounds__(256) void k_init(int* cnt, float* smallbuf, int N) {
    int i = blockIdx.x * 256 + threadIdx.x;
    if (i < N) cnt[i] = 0;
    if (i < 130) smallbuf[i] = 0.0f;  // sumvec[64] | svec[64] | loss[2]
}

// ---------------- degree histogram over dst (int) --------------------------
__global__ __launch_bounds__(256) void k_count(const int* __restrict__ dst,
                                               int* __restrict__ cnt, int E) {
    int e = blockIdx.x * 256 + threadIdx.x;
    if (e < E) atomicAdd(&cnt[dst[e]], 1);
}

// ---------------- scan stage 1: per-1024-chunk sums ------------------------
__global__ __launch_bounds__(256) void k_scan1(const int* __restrict__ cnt,
                                               int* __restrict__ partial, int N) {
    __shared__ int red[256];
    int base = blockIdx.x * 1024;
    int s = 0;
    for (int i = threadIdx.x; i < 1024; i += 256) {
        int idx = base + i;
        if (idx < N) s += cnt[idx];
    }
    red[threadIdx.x] = s;
    __syncthreads();
    for (int off = 128; off; off >>= 1) {
        if (threadIdx.x < off) red[threadIdx.x] += red[threadIdx.x + off];
        __syncthreads();
    }
    if (threadIdx.x == 0) partial[blockIdx.x] = red[0];
}

// ---------------- scan stage 2: serial scan of partials (B ~ 98) -----------
__global__ void k_scan2(int* partial, int B) {
    int acc = 0;
    for (int i = 0; i < B; i++) { int v = partial[i]; partial[i] = acc; acc += v; }
}

// ---------------- scan stage 3: block scan -> rowptr, cursor, dinv ---------
__global__ __launch_bounds__(256) void k_scan3(const int* __restrict__ cnt,
                                               const int* __restrict__ partial,
                                               int* __restrict__ rowptr,
                                               int* __restrict__ cursor,
                                               float* __restrict__ dinv,
                                               int N, int E) {
    __shared__ int sc[256];
    int base = blockIdx.x * 1024;
    int i0 = base + threadIdx.x * 4;
    int v0 = 0, v1 = 0, v2 = 0, v3 = 0;
    if (i0 + 3 < N) {
        int4 c = *(const int4*)(cnt + i0);
        v0 = c.x; v1 = c.y; v2 = c.z; v3 = c.w;
    } else {
        if (i0 < N)     v0 = cnt[i0];
        if (i0 + 1 < N) v1 = cnt[i0 + 1];
        if (i0 + 2 < N) v2 = cnt[i0 + 2];
        if (i0 + 3 < N) v3 = cnt[i0 + 3];
    }
    int s = v0 + v1 + v2 + v3;
    sc[threadIdx.x] = s;
    __syncthreads();
    for (int off = 1; off < 256; off <<= 1) {
        int t = (threadIdx.x >= off) ? sc[threadIdx.x - off] : 0;
        __syncthreads();
        sc[threadIdx.x] += t;
        __syncthreads();
    }
    int ex = sc[threadIdx.x] - s + partial[blockIdx.x];
    int r0 = ex, r1 = ex + v0, r2 = ex + v0 + v1, r3 = ex + v0 + v1 + v2;
    if (i0 < N)     { rowptr[i0]   = r0; cursor[i0]   = r0; dinv[i0]   = rsqrtf((float)(v0 + 1)); }
    if (i0 + 1 < N) { rowptr[i0+1] = r1; cursor[i0+1] = r1; dinv[i0+1] = rsqrtf((float)(v1 + 1)); }
    if (i0 + 2 < N) { rowptr[i0+2] = r2; cursor[i0+2] = r2; dinv[i0+2] = rsqrtf((float)(v2 + 1)); }
    if (i0 + 3 < N) { rowptr[i0+3] = r3; cursor[i0+3] = r3; dinv[i0+3] = rsqrtf((float)(v3 + 1)); }
    if (blockIdx.x == 0 && threadIdx.x == 0) rowptr[N] = E;
}

// ---------------- bucket fill: csr[j] = {src, perm[src]} -------------------
__global__ __launch_bounds__(256) void k_fill(const int* __restrict__ src,
                                              const int* __restrict__ dst,
                                              const int* __restrict__ perm,
                                              int* __restrict__ cursor,
                                              int2* __restrict__ csr, int E) {
    int e = blockIdx.x * 256 + threadIdx.x;
    if (e >= E) return;
    int d = dst[e], s = src[e];
    int j = atomicAdd(&cursor[d], 1);
    csr[j] = make_int2(s, perm[s]);
}

// ---------------- H = x @ W  (N x 128) @ (128 x 64) ------------------------
__global__ __launch_bounds__(256) void k_gemm(const float* __restrict__ x,
                                              const float* __restrict__ W,
                                              float* __restrict__ H, int N) {
    __shared__ float Xs[64 * 132];
    __shared__ float Ws[128 * 64];
    int tid = threadIdx.x;
    int row0 = blockIdx.x * 64;

    const float4* W4 = (const float4*)W;
    float4* Ws4 = (float4*)Ws;
#pragma unroll
    for (int i = 0; i < 8; i++) Ws4[tid + 256 * i] = W4[tid + 256 * i];

#pragma unroll
    for (int i = 0; i < 8; i++) {
        int j = tid + 256 * i;
        int r = j >> 5, c4 = j & 31;
        int row = row0 + r;
        float4 v = make_float4(0.f, 0.f, 0.f, 0.f);
        if (row < N) v = *(const float4*)(x + row * INDIM + c4 * 4);
        *(float4*)(&Xs[r * 132 + c4 * 4]) = v;
    }
    __syncthreads();

    int tx = tid & 15;
    int ty = tid >> 4;
    float acc[4][4] = {};
    const float* xa = &Xs[(ty * 4) * 132];
#pragma unroll 4
    for (int k = 0; k < 128; k++) {
        float4 b = *(const float4*)(&Ws[k * 64 + tx * 4]);
#pragma unroll
        for (int i = 0; i < 4; i++) {
            float a = xa[i * 132 + k];
            acc[i][0] = fmaf(a, b.x, acc[i][0]);
            acc[i][1] = fmaf(a, b.y, acc[i][1]);
            acc[i][2] = fmaf(a, b.z, acc[i][2]);
            acc[i][3] = fmaf(a, b.w, acc[i][3]);
        }
    }
#pragma unroll
    for (int i = 0; i < 4; i++) {
        int row = row0 + ty * 4 + i;
        if (row < N)
            *(float4*)(&H[row * HID + tx * 4]) =
                make_float4(acc[i][0], acc[i][1], acc[i][2], acc[i][3]);
    }
}

// ---------------- fused pull-gather + self-loop + bias + PReLU + colsum ----
__global__ __launch_bounds__(256) void k_gather(const float* __restrict__ H,
                                                const int* __restrict__ rowptr,
                                                const int2* __restrict__ csr,
                                                const int* __restrict__ perm,
                                                const float* __restrict__ dinv,
                                                const float* __restrict__ b,
                                                const float* __restrict__ a,
                                                float* __restrict__ pos,
                                                float* __restrict__ neg,
                                                float* __restrict__ sumvec, int N) {
    int lane = threadIdx.x & 63;
    int wid = (blockIdx.x * 256 + threadIdx.x) >> 6;
    int nw = gridDim.x * 4;
    float bD = b[lane], aD = a[lane];
    float sumAcc = 0.f;

    for (int n = wid; n < N; n += nw) {
        float dv = dinv[n];
        float w2 = dv * dv;
        float accP = H[(size_t)n * HID + lane] * w2;
        float accN = H[(size_t)perm[n] * HID + lane] * w2;
        int beg = rowptr[n], end = rowptr[n + 1];
        int2 ent;
        if (beg < end) ent = csr[beg];
        for (int j = beg; j < end; ++j) {
            int2 cur = ent;
            if (j + 1 < end) ent = csr[j + 1];
            float nrm = dinv[cur.x] * dv;
            accP += H[(size_t)cur.x * HID + lane] * nrm;
            accN += H[(size_t)cur.y * HID + lane] * nrm;
        }
        float vp = accP + bD; vp = vp > 0.f ? vp : vp * aD;
        float vn = accN + bD; vn = vn > 0.f ? vn : vn * aD;
        pos[(size_t)n * HID + lane] = vp;
        neg[(size_t)n * HID + lane] = vn;
        sumAcc += vp;
    }

    __shared__ float red[4][64];
    int w = threadIdx.x >> 6;
    red[w][lane] = sumAcc;
    __syncthreads();
    if (w == 0) {
        float s = red[0][lane] + red[1][lane] + red[2][lane] + red[3][lane];
        atomicAdd(&sumvec[lane], s);
    }
}

// ---------------- discriminator: summary = sigmoid(mean), s = Wd @ summary -
__global__ void k_disc(const float* __restrict__ sumvec, const float* __restrict__ Wd,
                       float* __restrict__ svec, int N) {
    __shared__ float summ[64];
    int t = threadIdx.x;  // 64 threads
    summ[t] = 1.f / (1.f + expf(-sumvec[t] / (float)N));
    __syncthreads();
    float s = 0.f;
#pragma unroll
    for (int j = 0; j < 64; j++) s += Wd[t * 64 + j] * summ[j];
    svec[t] = s;
}

// ---------------- logits + softplus sums -----------------------------------
__global__ __launch_bounds__(256) void k_loss(const float* __restrict__ pos,
                                              const float* __restrict__ neg,
                                              const float* __restrict__ svec,
                                              float* __restrict__ lossAcc, int N) {
    int lane = threadIdx.x & 63;
    int wid = (blockIdx.x * 256 + threadIdx.x) >> 6;
    int nw = gridDim.x * 4;
    float sd = svec[lane];
    float l1 = 0.f, l2 = 0.f;
    for (int n = wid; n < N; n += nw) {
        float p = pos[(size_t)n * HID + lane] * sd;
        float q = neg[(size_t)n * HID + lane] * sd;
#pragma unroll
        for (int off = 32; off; off >>= 1) {
            p += __shfl_xor(p, off);
            q += __shfl_xor(q, off);
        }
        if (lane == 0) {
            l1 += softplusf(-p);
            l2 += softplusf(q);
        }
    }
    __shared__ float redA[4], redB[4];
    int w = threadIdx.x >> 6;
    if (lane == 0) { redA[w] = l1; redB[w] = l2; }
    __syncthreads();
    if (threadIdx.x == 0) {
        atomicAdd(&lossAcc[0], redA[0] + redA[1] + redA[2] + redA[3]);
        atomicAdd(&lossAcc[1], redB[0] + redB[1] + redB[2] + redB[3]);
    }
}

// ---------------- final scalar ---------------------------------------------
__global__ void k_final(const float* __restrict__ lossAcc, float* __restrict__ out, int N) {
    out[0] = (lossAcc[0] + lossAcc[1]) / (float)N;
}

extern "C" void kernel_launch(void* const* d_in, const int* in_sizes, int n_in,
                              void* d_out, int out_size, void* d_ws, size_t ws_size,
                              hipStream_t stream) {
    const float* x      = (const float*)d_in[0];
    const float* W_gcn  = (const float*)d_in[1];
    const float* b_gcn  = (const float*)d_in[2];
    const float* prelu_a= (const float*)d_in[3];
    const float* W_disc = (const float*)d_in[4];
    const int*   eidx   = (const int*)d_in[5];
    const int*   perm   = (const int*)d_in[6];

    int N = in_sizes[0] / INDIM;      // 100000
    int E = in_sizes[5] / 2;          // 1600000
    const int* src = eidx;
    const int* dst = eidx + E;

    // workspace layout (4-byte units, keep 16B-ish alignment by ordering)
    float* ws = (float*)d_ws;
    size_t NH = (size_t)N * HID;          // 6.4M
    float* H      = ws;                    // NH floats
    float* pos    = ws + NH;               // NH
    float* neg    = ws + 2 * NH;           // NH
    int2*  csr    = (int2*)(ws + 3 * NH);  // E int2 = 2E ints
    int*   cnt    = (int*)(ws + 3 * NH) + 2 * (size_t)E;  // N
    int*   rowptr = cnt + N;               // N+1
    int*   cursor = rowptr + N + 1;        // N
    float* dinv   = (float*)(cursor + N);  // N
    int*   partial= (int*)(dinv + N);      // 128
    float* smallb = (float*)(partial + 128); // 130
    float* sumvec = smallb;
    float* svec   = smallb + 64;
    float* lossAcc= smallb + 128;

    int nblk;
    int B = (N + 1023) / 1024;            // scan chunks (98)

    nblk = (N + 255) / 256;
    k_init<<<nblk, 256, 0, stream>>>(cnt, smallb, N);

    nblk = (E + 255) / 256;
    k_count<<<nblk, 256, 0, stream>>>(dst, cnt, E);

    k_scan1<<<B, 256, 0, stream>>>(cnt, partial, N);
    k_scan2<<<1, 1, 0, stream>>>(partial, B);
    k_scan3<<<B, 256, 0, stream>>>(cnt, partial, rowptr, cursor, dinv, N, E);

    nblk = (N + 63) / 64;
    k_gemm<<<nblk, 256, 0, stream>>>(x, W_gcn, H, N);

    nblk = (E + 255) / 256;
    k_fill<<<nblk, 256, 0, stream>>>(src, dst, perm, cursor, csr, E);

    k_gather<<<2048, 256, 0, stream>>>(H, rowptr, csr, perm, dinv, b_gcn, prelu_a,
                                       pos, neg, sumvec, N);

    k_disc<<<1, 64, 0, stream>>>(sumvec, W_disc, svec, N);

    k_loss<<<512, 256, 0, stream>>>(pos, neg, svec, lossAcc, N);

    k_final<<<1, 1, 0, stream>>>(lossAcc, (float*)d_out, N);
}

// Round 4
// 403.195 us; speedup vs baseline: 2.1888x; 1.1352x over previous
//
#include <hip/hip_runtime.h>

#define HID 64
#define INDIM 128

typedef unsigned short ushort_t;
typedef unsigned int uint_t;

__device__ __forceinline__ float softplusf(float x) {
    return fmaxf(x, 0.f) + log1pf(expf(-fabsf(x)));
}
__device__ __forceinline__ float bf2f(ushort_t u) {
    union { uint_t i; float f; } c; c.i = ((uint_t)u) << 16; return c.f;
}
__device__ __forceinline__ ushort_t f2bf(float f) {
    union { float f; uint_t i; } c; c.f = f;
    uint_t u = c.i;
    u += 0x7FFFu + ((u >> 16) & 1u);   // round to nearest even
    return (ushort_t)(u >> 16);
}

// ---------------- degree histogram over dst (int) --------------------------
__global__ __launch_bounds__(256) void k_count(const int* __restrict__ dst,
                                               int* __restrict__ cnt, int E) {
    int e = blockIdx.x * 256 + threadIdx.x;
    if (e < E) atomicAdd(&cnt[dst[e]], 1);
}

// ---------------- scan stage 1: per-1024-chunk sums ------------------------
__global__ __launch_bounds__(256) void k_scan1(const int* __restrict__ cnt,
                                               int* __restrict__ partial, int N) {
    __shared__ int red[256];
    int base = blockIdx.x * 1024;
    int s = 0;
    for (int i = threadIdx.x; i < 1024; i += 256) {
        int idx = base + i;
        if (idx < N) s += cnt[idx];
    }
    red[threadIdx.x] = s;
    __syncthreads();
    for (int off = 128; off; off >>= 1) {
        if (threadIdx.x < off) red[threadIdx.x] += red[threadIdx.x + off];
        __syncthreads();
    }
    if (threadIdx.x == 0) partial[blockIdx.x] = red[0];
}

// ---------------- scan stage 2: one-block parallel exclusive scan ----------
__global__ __launch_bounds__(128) void k_scan2(int* partial, int B) {
    __shared__ int s[128];
    int t = threadIdx.x;
    int v = (t < B) ? partial[t] : 0;
    s[t] = v;
    __syncthreads();
    for (int off = 1; off < 128; off <<= 1) {
        int tmp = (t >= off) ? s[t - off] : 0;
        __syncthreads();
        s[t] += tmp;
        __syncthreads();
    }
    if (t < B) partial[t] = s[t] - v;   // exclusive
}

// ---------------- scan stage 3: block scan -> rowptr, cursor, dinv ---------
__global__ __launch_bounds__(256) void k_scan3(const int* __restrict__ cnt,
                                               const int* __restrict__ partial,
                                               int* __restrict__ rowptr,
                                               int* __restrict__ cursor,
                                               float* __restrict__ dinv,
                                               int N, int E) {
    __shared__ int sc[256];
    int base = blockIdx.x * 1024;
    int i0 = base + threadIdx.x * 4;
    int v0 = 0, v1 = 0, v2 = 0, v3 = 0;
    if (i0 + 3 < N) {
        int4 c = *(const int4*)(cnt + i0);
        v0 = c.x; v1 = c.y; v2 = c.z; v3 = c.w;
    } else {
        if (i0 < N)     v0 = cnt[i0];
        if (i0 + 1 < N) v1 = cnt[i0 + 1];
        if (i0 + 2 < N) v2 = cnt[i0 + 2];
        if (i0 + 3 < N) v3 = cnt[i0 + 3];
    }
    int s = v0 + v1 + v2 + v3;
    sc[threadIdx.x] = s;
    __syncthreads();
    for (int off = 1; off < 256; off <<= 1) {
        int t = (threadIdx.x >= off) ? sc[threadIdx.x - off] : 0;
        __syncthreads();
        sc[threadIdx.x] += t;
        __syncthreads();
    }
    int ex = sc[threadIdx.x] - s + partial[blockIdx.x];
    int r0 = ex, r1 = ex + v0, r2 = ex + v0 + v1, r3 = ex + v0 + v1 + v2;
    if (i0 < N)     { rowptr[i0]   = r0; cursor[i0]   = r0; dinv[i0]   = rsqrtf((float)(v0 + 1)); }
    if (i0 + 1 < N) { rowptr[i0+1] = r1; cursor[i0+1] = r1; dinv[i0+1] = rsqrtf((float)(v1 + 1)); }
    if (i0 + 2 < N) { rowptr[i0+2] = r2; cursor[i0+2] = r2; dinv[i0+2] = rsqrtf((float)(v2 + 1)); }
    if (i0 + 3 < N) { rowptr[i0+3] = r3; cursor[i0+3] = r3; dinv[i0+3] = rsqrtf((float)(v3 + 1)); }
    if (blockIdx.x == 0 && threadIdx.x == 0) rowptr[N] = E;
}

// ---------------- bucket fill: csr[j] = {src, perm[src]} -------------------
__global__ __launch_bounds__(256) void k_fill(const int* __restrict__ src,
                                              const int* __restrict__ dst,
                                              const int* __restrict__ perm,
                                              int* __restrict__ cursor,
                                              int2* __restrict__ csr, int E) {
    int e = blockIdx.x * 256 + threadIdx.x;
    if (e >= E) return;
    int d = dst[e], s = src[e];
    int j = atomicAdd(&cursor[d], 1);
    csr[j] = make_int2(s, perm[s]);
}

// ---------------- H = x @ W, output bf16 -----------------------------------
__global__ __launch_bounds__(256) void k_gemm(const float* __restrict__ x,
                                              const float* __restrict__ W,
                                              ushort_t* __restrict__ Hb, int N) {
    __shared__ float Xs[64 * 132];
    __shared__ float Ws[128 * 64];
    int tid = threadIdx.x;
    int row0 = blockIdx.x * 64;

    const float4* W4 = (const float4*)W;
    float4* Ws4 = (float4*)Ws;
#pragma unroll
    for (int i = 0; i < 8; i++) Ws4[tid + 256 * i] = W4[tid + 256 * i];

#pragma unroll
    for (int i = 0; i < 8; i++) {
        int j = tid + 256 * i;
        int r = j >> 5, c4 = j & 31;
        int row = row0 + r;
        float4 v = make_float4(0.f, 0.f, 0.f, 0.f);
        if (row < N) v = *(const float4*)(x + row * INDIM + c4 * 4);
        *(float4*)(&Xs[r * 132 + c4 * 4]) = v;
    }
    __syncthreads();

    int tx = tid & 15;
    int ty = tid >> 4;
    float acc[4][4] = {};
    const float* xa = &Xs[(ty * 4) * 132];
#pragma unroll 4
    for (int k = 0; k < 128; k++) {
        float4 b = *(const float4*)(&Ws[k * 64 + tx * 4]);
#pragma unroll
        for (int i = 0; i < 4; i++) {
            float a = xa[i * 132 + k];
            acc[i][0] = fmaf(a, b.x, acc[i][0]);
            acc[i][1] = fmaf(a, b.y, acc[i][1]);
            acc[i][2] = fmaf(a, b.z, acc[i][2]);
            acc[i][3] = fmaf(a, b.w, acc[i][3]);
        }
    }
#pragma unroll
    for (int i = 0; i < 4; i++) {
        int row = row0 + ty * 4 + i;
        if (row < N) {
            ushort4 o;
            o.x = f2bf(acc[i][0]); o.y = f2bf(acc[i][1]);
            o.z = f2bf(acc[i][2]); o.w = f2bf(acc[i][3]);
            *(ushort4*)(&Hb[(size_t)row * HID + tx * 4]) = o;
        }
    }
}

// ---------------- fused pull-gather + self-loop + bias + PReLU + colsum ----
__global__ __launch_bounds__(256) void k_gather(const ushort_t* __restrict__ Hb,
                                                const int* __restrict__ rowptr,
                                                const int2* __restrict__ csr,
                                                const int* __restrict__ perm,
                                                const float* __restrict__ dinv,
                                                const float* __restrict__ b,
                                                const float* __restrict__ a,
                                                ushort_t* __restrict__ posb,
                                                ushort_t* __restrict__ negb,
                                                float* __restrict__ sumvec, int N) {
    int lane = threadIdx.x & 63;
    int wid = (blockIdx.x * 256 + threadIdx.x) >> 6;
    int nw = gridDim.x * 4;
    float bD = b[lane], aD = a[lane];
    float sumAcc = 0.f;

    for (int n = wid; n < N; n += nw) {
        float dv = dinv[n];
        float w2 = dv * dv;
        float accP = bf2f(Hb[(size_t)n * HID + lane]) * w2;
        float accN = bf2f(Hb[(size_t)perm[n] * HID + lane]) * w2;
        int beg = rowptr[n], end = rowptr[n + 1];
        int2 ent;
        if (beg < end) ent = csr[beg];
        for (int j = beg; j < end; ++j) {
            int2 cur = ent;
            if (j + 1 < end) ent = csr[j + 1];
            float nrm = dinv[cur.x] * dv;
            accP += bf2f(Hb[(size_t)cur.x * HID + lane]) * nrm;
            accN += bf2f(Hb[(size_t)cur.y * HID + lane]) * nrm;
        }
        float vp = accP + bD; vp = vp > 0.f ? vp : vp * aD;
        float vn = accN + bD; vn = vn > 0.f ? vn : vn * aD;
        posb[(size_t)n * HID + lane] = f2bf(vp);
        negb[(size_t)n * HID + lane] = f2bf(vn);
        sumAcc += vp;
    }

    __shared__ float red[4][64];
    int w = threadIdx.x >> 6;
    red[w][lane] = sumAcc;
    __syncthreads();
    if (w == 0) {
        float s = red[0][lane] + red[1][lane] + red[2][lane] + red[3][lane];
        atomicAdd(&sumvec[lane], s);
    }
}

// ---------------- discriminator: summary = sigmoid(mean), s = Wd @ summary -
__global__ void k_disc(const float* __restrict__ sumvec, const float* __restrict__ Wd,
                       float* __restrict__ svec, int N) {
    __shared__ float summ[64];
    int t = threadIdx.x;  // 64 threads
    summ[t] = 1.f / (1.f + expf(-sumvec[t] / (float)N));
    __syncthreads();
    float s = 0.f;
#pragma unroll
    for (int j = 0; j < 64; j++) s += Wd[t * 64 + j] * summ[j];
    svec[t] = s;
}

// ---------------- logits + softplus sums -----------------------------------
__global__ __launch_bounds__(256) void k_loss(const ushort_t* __restrict__ posb,
                                              const ushort_t* __restrict__ negb,
                                              const float* __restrict__ svec,
                                              float* __restrict__ lossAcc, int N) {
    int lane = threadIdx.x & 63;
    int wid = (blockIdx.x * 256 + threadIdx.x) >> 6;
    int nw = gridDim.x * 4;
    float sd = svec[lane];
    float l1 = 0.f, l2 = 0.f;
    for (int n = wid; n < N; n += nw) {
        float p = bf2f(posb[(size_t)n * HID + lane]) * sd;
        float q = bf2f(negb[(size_t)n * HID + lane]) * sd;
#pragma unroll
        for (int off = 32; off; off >>= 1) {
            p += __shfl_xor(p, off);
            q += __shfl_xor(q, off);
        }
        if (lane == 0) {
            l1 += softplusf(-p);
            l2 += softplusf(q);
        }
    }
    __shared__ float redA[4], redB[4];
    int w = threadIdx.x >> 6;
    if (lane == 0) { redA[w] = l1; redB[w] = l2; }
    __syncthreads();
    if (threadIdx.x == 0) {
        atomicAdd(&lossAcc[0], redA[0] + redA[1] + redA[2] + redA[3]);
        atomicAdd(&lossAcc[1], redB[0] + redB[1] + redB[2] + redB[3]);
    }
}

// ---------------- final scalar ---------------------------------------------
__global__ void k_final(const float* __restrict__ lossAcc, float* __restrict__ out, int N) {
    out[0] = (lossAcc[0] + lossAcc[1]) / (float)N;
}

extern "C" void kernel_launch(void* const* d_in, const int* in_sizes, int n_in,
                              void* d_out, int out_size, void* d_ws, size_t ws_size,
                              hipStream_t stream) {
    const float* x      = (const float*)d_in[0];
    const float* W_gcn  = (const float*)d_in[1];
    const float* b_gcn  = (const float*)d_in[2];
    const float* prelu_a= (const float*)d_in[3];
    const float* W_disc = (const float*)d_in[4];
    const int*   eidx   = (const int*)d_in[5];
    const int*   perm   = (const int*)d_in[6];

    int N = in_sizes[0] / INDIM;      // 100000
    int E = in_sizes[5] / 2;          // 1600000
    const int* src = eidx;
    const int* dst = eidx + E;

    // byte-offset workspace layout, 256B-aligned segments
    char* base = (char*)d_ws;
    size_t off = 0;
    auto alloc = [&](size_t bytes) { size_t o = off; off = (off + bytes + 255) & ~(size_t)255; return o; };
    ushort_t* Hb    = (ushort_t*)(base + alloc((size_t)N * HID * 2));
    ushort_t* posb  = (ushort_t*)(base + alloc((size_t)N * HID * 2));
    ushort_t* negb  = (ushort_t*)(base + alloc((size_t)N * HID * 2));
    int2*     csr   = (int2*)   (base + alloc((size_t)E * 8));
    // cnt and smallb contiguous: single memset clears both
    size_t cntOff   = alloc((size_t)N * 4 + 130 * 4);
    int*      cnt   = (int*)(base + cntOff);
    float*    smallb= (float*)(base + cntOff + (size_t)N * 4);
    int*      rowptr= (int*)  (base + alloc(((size_t)N + 1) * 4));
    int*      cursor= (int*)  (base + alloc((size_t)N * 4));
    float*    dinv  = (float*)(base + alloc((size_t)N * 4));
    int*      partial=(int*)  (base + alloc(128 * 4));
    float* sumvec = smallb;
    float* svec   = smallb + 64;
    float* lossAcc= smallb + 128;

    int nblk;
    int B = (N + 1023) / 1024;            // scan chunks (98)

    hipMemsetAsync(cnt, 0, (size_t)N * 4 + 130 * 4, stream);

    nblk = (E + 255) / 256;
    k_count<<<nblk, 256, 0, stream>>>(dst, cnt, E);

    k_scan1<<<B, 256, 0, stream>>>(cnt, partial, N);
    k_scan2<<<1, 128, 0, stream>>>(partial, B);
    k_scan3<<<B, 256, 0, stream>>>(cnt, partial, rowptr, cursor, dinv, N, E);

    nblk = (N + 63) / 64;
    k_gemm<<<nblk, 256, 0, stream>>>(x, W_gcn, Hb, N);

    nblk = (E + 255) / 256;
    k_fill<<<nblk, 256, 0, stream>>>(src, dst, perm, cursor, csr, E);

    k_gather<<<2048, 256, 0, stream>>>(Hb, rowptr, csr, perm, dinv, b_gcn, prelu_a,
                                       posb, negb, sumvec, N);

    k_disc<<<1, 64, 0, stream>>>(sumvec, W_disc, svec, N);

    k_loss<<<512, 256, 0, stream>>>(posb, negb, svec, lossAcc, N);

    k_final<<<1, 1, 0, stream>>>(lossAcc, (float*)d_out, N);
}

// Round 5
// 400.475 us; speedup vs baseline: 2.2037x; 1.0068x over previous
//
#include <hip/hip_runtime.h>

#define HID 64
#define INDIM 128

typedef unsigned short ushort_t;
typedef unsigned int uint_t;

__device__ __forceinline__ float softplusf(float x) {
    return fmaxf(x, 0.f) + log1pf(expf(-fabsf(x)));
}
__device__ __forceinline__ float bf2f(ushort_t u) {
    union { uint_t i; float f; } c; c.i = ((uint_t)u) << 16; return c.f;
}
__device__ __forceinline__ ushort_t f2bf(float f) {
    union { float f; uint_t i; } c; c.f = f;
    uint_t u = c.i;
    u += 0x7FFFu + ((u >> 16) & 1u);   // round to nearest even
    return (ushort_t)(u >> 16);
}
// low/high bf16 of a packed u32 -> float
__device__ __forceinline__ float lo_bf(uint_t u) {
    union { uint_t i; float f; } c; c.i = u << 16; return c.f;
}
__device__ __forceinline__ float hi_bf(uint_t u) {
    union { uint_t i; float f; } c; c.i = u & 0xFFFF0000u; return c.f;
}

// ---------------- degree histogram over dst (int) --------------------------
__global__ __launch_bounds__(256) void k_count(const int* __restrict__ dst,
                                               int* __restrict__ cnt, int E) {
    int e = blockIdx.x * 256 + threadIdx.x;
    if (e < E) atomicAdd(&cnt[dst[e]], 1);
}

// ---------------- scan stage 1: per-1024-chunk sums ------------------------
__global__ __launch_bounds__(256) void k_scan1(const int* __restrict__ cnt,
                                               int* __restrict__ partial, int N) {
    __shared__ int red[256];
    int base = blockIdx.x * 1024;
    int s = 0;
    for (int i = threadIdx.x; i < 1024; i += 256) {
        int idx = base + i;
        if (idx < N) s += cnt[idx];
    }
    red[threadIdx.x] = s;
    __syncthreads();
    for (int off = 128; off; off >>= 1) {
        if (threadIdx.x < off) red[threadIdx.x] += red[threadIdx.x + off];
        __syncthreads();
    }
    if (threadIdx.x == 0) partial[blockIdx.x] = red[0];
}

// ---------------- scan stage 2: one-block parallel exclusive scan ----------
__global__ __launch_bounds__(128) void k_scan2(int* partial, int B) {
    __shared__ int s[128];
    int t = threadIdx.x;
    int v = (t < B) ? partial[t] : 0;
    s[t] = v;
    __syncthreads();
    for (int off = 1; off < 128; off <<= 1) {
        int tmp = (t >= off) ? s[t - off] : 0;
        __syncthreads();
        s[t] += tmp;
        __syncthreads();
    }
    if (t < B) partial[t] = s[t] - v;   // exclusive
}

// ---------------- scan stage 3: block scan -> rowptr, cursor, dinv ---------
__global__ __launch_bounds__(256) void k_scan3(const int* __restrict__ cnt,
                                               const int* __restrict__ partial,
                                               int* __restrict__ rowptr,
                                               int* __restrict__ cursor,
                                               float* __restrict__ dinv,
                                               int N, int E) {
    __shared__ int sc[256];
    int base = blockIdx.x * 1024;
    int i0 = base + threadIdx.x * 4;
    int v0 = 0, v1 = 0, v2 = 0, v3 = 0;
    if (i0 + 3 < N) {
        int4 c = *(const int4*)(cnt + i0);
        v0 = c.x; v1 = c.y; v2 = c.z; v3 = c.w;
    } else {
        if (i0 < N)     v0 = cnt[i0];
        if (i0 + 1 < N) v1 = cnt[i0 + 1];
        if (i0 + 2 < N) v2 = cnt[i0 + 2];
        if (i0 + 3 < N) v3 = cnt[i0 + 3];
    }
    int s = v0 + v1 + v2 + v3;
    sc[threadIdx.x] = s;
    __syncthreads();
    for (int off = 1; off < 256; off <<= 1) {
        int t = (threadIdx.x >= off) ? sc[threadIdx.x - off] : 0;
        __syncthreads();
        sc[threadIdx.x] += t;
        __syncthreads();
    }
    int ex = sc[threadIdx.x] - s + partial[blockIdx.x];
    int r0 = ex, r1 = ex + v0, r2 = ex + v0 + v1, r3 = ex + v0 + v1 + v2;
    if (i0 < N)     { rowptr[i0]   = r0; cursor[i0]   = r0; dinv[i0]   = rsqrtf((float)(v0 + 1)); }
    if (i0 + 1 < N) { rowptr[i0+1] = r1; cursor[i0+1] = r1; dinv[i0+1] = rsqrtf((float)(v1 + 1)); }
    if (i0 + 2 < N) { rowptr[i0+2] = r2; cursor[i0+2] = r2; dinv[i0+2] = rsqrtf((float)(v2 + 1)); }
    if (i0 + 3 < N) { rowptr[i0+3] = r3; cursor[i0+3] = r3; dinv[i0+3] = rsqrtf((float)(v3 + 1)); }
    if (blockIdx.x == 0 && threadIdx.x == 0) rowptr[N] = E;
}

// ---------------- bucket fill: csr[j] = {src, perm[src]} -------------------
__global__ __launch_bounds__(256) void k_fill(const int* __restrict__ src,
                                              const int* __restrict__ dst,
                                              const int* __restrict__ perm,
                                              int* __restrict__ cursor,
                                              int2* __restrict__ csr, int E) {
    int e = blockIdx.x * 256 + threadIdx.x;
    if (e >= E) return;
    int d = dst[e], s = src[e];
    int j = atomicAdd(&cursor[d], 1);
    csr[j] = make_int2(s, perm[s]);
}

// ---------------- H = x @ W, output bf16 -----------------------------------
__global__ __launch_bounds__(256) void k_gemm(const float* __restrict__ x,
                                              const float* __restrict__ W,
                                              ushort_t* __restrict__ Hb, int N) {
    __shared__ float Xs[64 * 132];
    __shared__ float Ws[128 * 64];
    int tid = threadIdx.x;
    int row0 = blockIdx.x * 64;

    const float4* W4 = (const float4*)W;
    float4* Ws4 = (float4*)Ws;
#pragma unroll
    for (int i = 0; i < 8; i++) Ws4[tid + 256 * i] = W4[tid + 256 * i];

#pragma unroll
    for (int i = 0; i < 8; i++) {
        int j = tid + 256 * i;
        int r = j >> 5, c4 = j & 31;
        int row = row0 + r;
        float4 v = make_float4(0.f, 0.f, 0.f, 0.f);
        if (row < N) v = *(const float4*)(x + row * INDIM + c4 * 4);
        *(float4*)(&Xs[r * 132 + c4 * 4]) = v;
    }
    __syncthreads();

    int tx = tid & 15;
    int ty = tid >> 4;
    float acc[4][4] = {};
    const float* xa = &Xs[(ty * 4) * 132];
#pragma unroll 4
    for (int k = 0; k < 128; k++) {
        float4 b = *(const float4*)(&Ws[k * 64 + tx * 4]);
#pragma unroll
        for (int i = 0; i < 4; i++) {
            float a = xa[i * 132 + k];
            acc[i][0] = fmaf(a, b.x, acc[i][0]);
            acc[i][1] = fmaf(a, b.y, acc[i][1]);
            acc[i][2] = fmaf(a, b.z, acc[i][2]);
            acc[i][3] = fmaf(a, b.w, acc[i][3]);
        }
    }
#pragma unroll
    for (int i = 0; i < 4; i++) {
        int row = row0 + ty * 4 + i;
        if (row < N) {
            ushort4 o;
            o.x = f2bf(acc[i][0]); o.y = f2bf(acc[i][1]);
            o.z = f2bf(acc[i][2]); o.w = f2bf(acc[i][3]);
            *(ushort4*)(&Hb[(size_t)row * HID + tx * 4]) = o;
        }
    }
}

// ---------------- fused pull-gather, 2-half layout, 4 edges/iter ----------
// lanes 0-31 (half 0) and 32-63 (half 1): each lane covers dims 2*sub, 2*sub+1
// half h handles edges j+h and j+2+h of each quad; at the end half 0 finishes
// pos (and column-sum), half 1 finishes neg.
__global__ __launch_bounds__(256) void k_gather(const ushort_t* __restrict__ Hb,
                                                const int* __restrict__ rowptr,
                                                const int2* __restrict__ csr,
                                                const int* __restrict__ perm,
                                                const float* __restrict__ dinv,
                                                const float* __restrict__ b,
                                                const float* __restrict__ a,
                                                ushort_t* __restrict__ posb,
                                                ushort_t* __restrict__ negb,
                                                float* __restrict__ sumvec, int N) {
    int tid = threadIdx.x;
    int lane = tid & 63;
    int half = lane >> 5;
    int sub = lane & 31;
    int wid = (blockIdx.x * 256 + tid) >> 6;
    int nw = gridDim.x * 4;
    const uint_t* H32 = (const uint_t*)Hb;     // row stride = 32 u32
    float2 b2 = ((const float2*)b)[sub];
    float2 a2 = ((const float2*)a)[sub];
    float sum0 = 0.f, sum1 = 0.f;

    for (int n = wid; n < N; n += nw) {
        float dv = dinv[n];
        float w2 = dv * dv;
        int beg = rowptr[n], end = rowptr[n + 1];
        float accP0 = 0.f, accP1 = 0.f, accN0 = 0.f, accN1 = 0.f;
        for (int j = beg; j < end; j += 4) {
            int eA = j + half;
            int eB = j + 2 + half;
            bool vA = eA < end, vB = eB < end;
            int2 spA = vA ? csr[eA] : make_int2(0, 0);
            int2 spB = vB ? csr[eB] : make_int2(0, 0);
            float ndA = vA ? dinv[spA.x] * dv : 0.f;
            float ndB = vB ? dinv[spB.x] * dv : 0.f;
            uint_t upA = H32[spA.x * 32 + sub];
            uint_t unA = H32[spA.y * 32 + sub];
            uint_t upB = H32[spB.x * 32 + sub];
            uint_t unB = H32[spB.y * 32 + sub];
            accP0 = fmaf(lo_bf(upA), ndA, accP0);
            accP1 = fmaf(hi_bf(upA), ndA, accP1);
            accN0 = fmaf(lo_bf(unA), ndA, accN0);
            accN1 = fmaf(hi_bf(unA), ndA, accN1);
            accP0 = fmaf(lo_bf(upB), ndB, accP0);
            accP1 = fmaf(hi_bf(upB), ndB, accP1);
            accN0 = fmaf(lo_bf(unB), ndB, accN0);
            accN1 = fmaf(hi_bf(unB), ndB, accN1);
        }
        // combine the two halves' partial edge sums
        accP0 += __shfl_xor(accP0, 32);
        accP1 += __shfl_xor(accP1, 32);
        accN0 += __shfl_xor(accN0, 32);
        accN1 += __shfl_xor(accN1, 32);
        // self-loop: half0 -> row n (pos), half1 -> row perm[n] (neg)
        int selfrow = half ? perm[n] : n;
        uint_t us = H32[selfrow * 32 + sub];
        float e0 = half ? accN0 : accP0;
        float e1 = half ? accN1 : accP1;
        float v0 = fmaf(lo_bf(us), w2, e0) + b2.x;
        float v1 = fmaf(hi_bf(us), w2, e1) + b2.y;
        v0 = v0 > 0.f ? v0 : v0 * a2.x;
        v1 = v1 > 0.f ? v1 : v1 * a2.y;
        uint_t packed = ((uint_t)f2bf(v1) << 16) | (uint_t)f2bf(v0);
        uint_t* outp = (uint_t*)(half ? negb : posb);
        outp[n * 32 + sub] = packed;
        if (!half) { sum0 += v0; sum1 += v1; }
    }

    __shared__ float red[4][64];
    int w = tid >> 6;
    if (!half) { red[w][2 * sub] = sum0; red[w][2 * sub + 1] = sum1; }
    __syncthreads();
    if (tid < 64) {
        float s = red[0][tid] + red[1][tid] + red[2][tid] + red[3][tid];
        atomicAdd(&sumvec[tid], s);
    }
}

// ---------------- discriminator: summary = sigmoid(mean), s = Wd @ summary -
__global__ void k_disc(const float* __restrict__ sumvec, const float* __restrict__ Wd,
                       float* __restrict__ svec, int N) {
    __shared__ float summ[64];
    int t = threadIdx.x;  // 64 threads
    summ[t] = 1.f / (1.f + expf(-sumvec[t] / (float)N));
    __syncthreads();
    float s = 0.f;
#pragma unroll
    for (int j = 0; j < 64; j++) s += Wd[t * 64 + j] * summ[j];
    svec[t] = s;
}

// ---------------- logits + softplus sums -----------------------------------
__global__ __launch_bounds__(256) void k_loss(const ushort_t* __restrict__ posb,
                                              const ushort_t* __restrict__ negb,
                                              const float* __restrict__ svec,
                                              float* __restrict__ lossAcc, int N) {
    int lane = threadIdx.x & 63;
    int wid = (blockIdx.x * 256 + threadIdx.x) >> 6;
    int nw = gridDim.x * 4;
    float sd = svec[lane];
    float l1 = 0.f, l2 = 0.f;
    for (int n = wid; n < N; n += nw) {
        float p = bf2f(posb[(size_t)n * HID + lane]) * sd;
        float q = bf2f(negb[(size_t)n * HID + lane]) * sd;
#pragma unroll
        for (int off = 32; off; off >>= 1) {
            p += __shfl_xor(p, off);
            q += __shfl_xor(q, off);
        }
        if (lane == 0) {
            l1 += softplusf(-p);
            l2 += softplusf(q);
        }
    }
    __shared__ float redA[4], redB[4];
    int w = threadIdx.x >> 6;
    if (lane == 0) { redA[w] = l1; redB[w] = l2; }
    __syncthreads();
    if (threadIdx.x == 0) {
        atomicAdd(&lossAcc[0], redA[0] + redA[1] + redA[2] + redA[3]);
        atomicAdd(&lossAcc[1], redB[0] + redB[1] + redB[2] + redB[3]);
    }
}

// ---------------- final scalar ---------------------------------------------
__global__ void k_final(const float* __restrict__ lossAcc, float* __restrict__ out, int N) {
    out[0] = (lossAcc[0] + lossAcc[1]) / (float)N;
}

extern "C" void kernel_launch(void* const* d_in, const int* in_sizes, int n_in,
                              void* d_out, int out_size, void* d_ws, size_t ws_size,
                              hipStream_t stream) {
    const float* x      = (const float*)d_in[0];
    const float* W_gcn  = (const float*)d_in[1];
    const float* b_gcn  = (const float*)d_in[2];
    const float* prelu_a= (const float*)d_in[3];
    const float* W_disc = (const float*)d_in[4];
    const int*   eidx   = (const int*)d_in[5];
    const int*   perm   = (const int*)d_in[6];

    int N = in_sizes[0] / INDIM;      // 100000
    int E = in_sizes[5] / 2;          // 1600000
    const int* src = eidx;
    const int* dst = eidx + E;

    // byte-offset workspace layout, 256B-aligned segments
    char* base = (char*)d_ws;
    size_t off = 0;
    auto alloc = [&](size_t bytes) { size_t o = off; off = (off + bytes + 255) & ~(size_t)255; return o; };
    ushort_t* Hb    = (ushort_t*)(base + alloc((size_t)N * HID * 2));
    ushort_t* posb  = (ushort_t*)(base + alloc((size_t)N * HID * 2));
    ushort_t* negb  = (ushort_t*)(base + alloc((size_t)N * HID * 2));
    int2*     csr   = (int2*)   (base + alloc((size_t)E * 8));
    // cnt and smallb contiguous: single memset clears both
    size_t cntOff   = alloc((size_t)N * 4 + 130 * 4);
    int*      cnt   = (int*)(base + cntOff);
    float*    smallb= (float*)(base + cntOff + (size_t)N * 4);
    int*      rowptr= (int*)  (base + alloc(((size_t)N + 1) * 4));
    int*      cursor= (int*)  (base + alloc((size_t)N * 4));
    float*    dinv  = (float*)(base + alloc((size_t)N * 4));
    int*      partial=(int*)  (base + alloc(128 * 4));
    float* sumvec = smallb;
    float* svec   = smallb + 64;
    float* lossAcc= smallb + 128;

    int nblk;
    int B = (N + 1023) / 1024;            // scan chunks (98)

    hipMemsetAsync(cnt, 0, (size_t)N * 4 + 130 * 4, stream);

    nblk = (E + 255) / 256;
    k_count<<<nblk, 256, 0, stream>>>(dst, cnt, E);

    k_scan1<<<B, 256, 0, stream>>>(cnt, partial, N);
    k_scan2<<<1, 128, 0, stream>>>(partial, B);
    k_scan3<<<B, 256, 0, stream>>>(cnt, partial, rowptr, cursor, dinv, N, E);

    nblk = (N + 63) / 64;
    k_gemm<<<nblk, 256, 0, stream>>>(x, W_gcn, Hb, N);

    nblk = (E + 255) / 256;
    k_fill<<<nblk, 256, 0, stream>>>(src, dst, perm, cursor, csr, E);

    k_gather<<<2048, 256, 0, stream>>>(Hb, rowptr, csr, perm, dinv, b_gcn, prelu_a,
                                       posb, negb, sumvec, N);

    k_disc<<<1, 64, 0, stream>>>(sumvec, W_disc, svec, N);

    k_loss<<<512, 256, 0, stream>>>(posb, negb, svec, lossAcc, N);

    k_final<<<1, 1, 0, stream>>>(lossAcc, (float*)d_out, N);
}